// Round 6
// baseline (181.166 us; speedup 1.0000x reference)
//
#include <hip/hip_runtime.h>

// FilteredNoiseGenerator: B=32, t=4000, nbands=65, framesize=80, L_fir=129, L=208
// out[b,p] = sum_{f,m} x[b,f,m]*w[b,f,tau], tau = (p+64) - 80f - m in [0,128]
// R6: P1 (firwin) is a GEMM with a FIXED matrix:
//   firwin[f][n] = sum_k H[f][k] * M[n][k],
//   M[n][k] = hann[n] * ((k==0?1:2)/129) * cos(2pi*k*(n-64)/129)
// -> mfma_f32_16x16x32_f16, M precomputed per-call into d_ws (frag-order,
//    coalesced). P2 gather conv unchanged from R5 (proven).

#define NT 256
#define X_STRIDE 84        // x row pad; /4=21 odd -> b128 starts spread
#define W_STRIDE 158       // max read idx 156 (proven); 158 mod 32 = 30, 2-way free
#define W_P 14             // w[tau] at wr[W_P+tau]; tau in [0,128]; zeros outside
#define NSLOT 35           // frames f0-2 .. f0+32
#define WTOT (NSLOT * W_STRIDE + 2)   // 5532 floats (mult of 4 for float4 zeroing)
#define UTOT (NSLOT * X_STRIDE)       // 2940 floats; union: H-f16 (P1) then x (P2)
#define HF_STRIDE 104      // f16 H row stride: 208 B (16B-aligned frags, 4-way max)

typedef _Float16 f16x8 __attribute__((ext_vector_type(8)));
typedef float f32x4 __attribute__((ext_vector_type(4)));

// ---- init: M in MFMA B-operand frag order. frag (nt,ks) of 27; within frag,
// lane holds B[k = ks*32 + (lane>>4)*8 + j][n = nt*16 + (lane&15)], j=0..7.
// Layout: M[((nt*3+ks)*64 + lane)*8 + j]  -> wave B-load = 1 coalesced b128/lane.
__global__ void __launch_bounds__(256)
minit_kernel(_Float16* __restrict__ M) {
  const float TP = 6.28318530717958647692f / 129.f;
  int i = blockIdx.x * 256 + threadIdx.x;      // 54*256 = 13824 = 27*512 exactly
  int frag = i >> 9;
  int off  = i & 511;
  int lane = off >> 3, j = off & 7;
  int nt = frag / 3, ks = frag - 3 * (frag / 3);
  int n = nt * 16 + (lane & 15);
  int k = ks * 32 + (lane >> 4) * 8 + j;
  float v = 0.f;
  if (n <= 128 && k <= 64) {
    float hann = 0.5f - 0.5f * __cosf((float)n * TP);
    float sc = (k == 0 ? 1.f : 2.f) * (1.f / 129.f);
    int e = (k * (n - 64)) % 129; if (e < 0) e += 129;   // exact arg reduction
    v = hann * sc * __cosf((float)e * TP);
  }
  M[i] = (_Float16)v;
}

__global__ void __launch_bounds__(NT)
fng_kernel(const float* __restrict__ Hg_, const float* __restrict__ Ng_,
           float* __restrict__ Og_, const _Float16* __restrict__ Mg) {
  __shared__ __align__(16) float sW[WTOT];   // 22,128 B  (firwin fp32, zero-padded)
  __shared__ __align__(16) float sU[UTOT];   // 11,760 B: H-f16 during P1, x during P2
  // total 33,888 B -> 4 wg/CU

  const int t  = threadIdx.x;
  const int bx = blockIdx.x;     // 0..124 (32 output-frames each)
  const int b  = blockIdx.y;     // 0..31
  const int f0 = bx * 32;

  // ---------------- P0: zero sW, H -> f16 LDS, noise -> regs ----------------
  float4 xq[3];                  // parked noise quads (raw; 0.5 -> maps to 0)
  {
    float4 z4 = {0.f, 0.f, 0.f, 0.f};
    for (int i = t; i < WTOT / 4; i += NT) ((float4*)sW)[i] = z4;
    _Float16* sHf = (_Float16*)sU;
    const float* Hg = Hg_ + (size_t)b * (4000 * 65);
    for (int i = t; i < 48 * 96; i += NT) {          // rows 0..47 (pad rows zero)
      int row = i / 96, k = i - 96 * (i / 96);
      int fr = f0 - 2 + row;
      float v = 0.f;
      if (k < 65 && row < NSLOT && fr >= 0 && fr < 4000) v = Hg[fr * 65 + k];
      sHf[row * HF_STRIDE + k] = (_Float16)v;
    }
    const float* Ng = Ng_ + (size_t)b * 320000;
#pragma unroll
    for (int j = 0; j < 3; ++j) {
      int q = t + 256 * j;
      float4 v = {0.5f, 0.5f, 0.5f, 0.5f};          // 2*0.5-1 = 0 for OOB rows
      if (q < NSLOT * 21) {
        int fi = q / 21, qm = q - fi * 21;
        int fr = f0 - 2 + fi;
        if (qm < 20 && fr >= 0 && fr < 4000)
          v = *(const float4*)&Ng[(size_t)fr * 80 + 4 * qm];
      }
      xq[j] = v;
    }
  }
  __syncthreads();

  // ------- P1: firwin = H x M^T via MFMA 16x16x32 f16 -------
  // Output [48 frames x 144 n] in 27 tiles (mt 0..2, nt 0..8); wave w takes
  // tiles w, w+4, ... (7/7/7/6). K = 96 (zero-padded) = 3 steps.
  // A: lane holds A[m=lane&15][k=quad*8+j] (m120-verified); B from Mg frag order;
  // C/D: col=lane&15 (n), row=quad*4+reg (frame) (m89-verified).
  {
    const _Float16* sHf = (const _Float16*)sU;
    const int wv   = t >> 6;
    const int lane = t & 63;
    const int quad = lane >> 4;
    const int l15  = lane & 15;
#pragma unroll 1
    for (int tile = wv; tile < 27; tile += 4) {
      const int mt = tile / 9, nt = tile - 9 * (tile / 9);
      f32x4 acc = {0.f, 0.f, 0.f, 0.f};
#pragma unroll
      for (int ks = 0; ks < 3; ++ks) {
        f16x8 a = *(const f16x8*)&sHf[(mt * 16 + l15) * HF_STRIDE + ks * 32 + quad * 8];
        f16x8 bb = ((const f16x8*)Mg)[(nt * 3 + ks) * 64 + lane];
        acc = __builtin_amdgcn_mfma_f32_16x16x32_f16(a, bb, acc, 0, 0, 0);
      }
      const int n = nt * 16 + l15;
      const int fr0 = mt * 16 + quad * 4;
      if (n <= 128) {
#pragma unroll
        for (int r = 0; r < 4; ++r) {
          int frame = fr0 + r;
          if (frame < NSLOT) sW[frame * W_STRIDE + W_P + n] = acc[r];
        }
      }
    }
  }
  __syncthreads();

  // ---------------- P1.5: park noise into sU (overwrites H region) ----------------
#pragma unroll
  for (int j = 0; j < 3; ++j) {
    int q = t + 256 * j;
    if (q < NSLOT * 21) {
      int fi = q / 21, qm = q - fi * 21;
      if (qm < 20) {                                // pad quad qm=20 never read
        float4 v = xq[j], o;
        o.x = 2.f * v.x - 1.f; o.y = 2.f * v.y - 1.f;
        o.z = 2.f * v.z - 1.f; o.w = 2.f * v.w - 1.f;
        *(float4*)&sU[fi * X_STRIDE + 4 * qm] = o;
      }
    }
  }
  __syncthreads();

  // ---------------- P2: gather convolution + direct stores (R5-proven) ----------------
  {
    const int col = t & 31;
    const int pb  = t >> 5;
    const int e   = 64 + 10 * pb;
    const int qq  = (e >= 80) ? 1 : 0;
    const int D   = e - 80 * qq;                    // per half-wave uniform
    float acc[10];
#pragma unroll
    for (int i = 0; i < 10; ++i) acc[i] = 0.f;

#pragma unroll 1
    for (int g = 2; g >= -1; --g) {                 // source frame F - g
      const int dlt = D + 80 * g;
      int Qlo = (dlt - 131 + 3) >> 2; if (Qlo < 0) Qlo = 0;
      int Qhi = (dlt + 9) >> 2;       if (Qhi > 19) Qhi = 19;
      if (Qlo > Qhi) continue;
      const int slot = col + qq - g + 2;            // 0..34
      const float* wr = &sW[slot * W_STRIDE];
      const float* xr = &sU[slot * X_STRIDE];
      int wb = W_P + dlt - 4 * Qlo - 4;             // window base (even, >=0)
      float wv[16];
#pragma unroll
      for (int k = 0; k < 8; ++k) {
        float2 w2 = *(const float2*)&wr[wb + 2 * k];
        wv[2 * k] = w2.x; wv[2 * k + 1] = w2.y;
      }
#pragma unroll 4                                    // period-4 rotation renames movs away
      for (int Q = Qlo; Q <= Qhi; ++Q) {
        float4 x4 = *(const float4*)&xr[4 * Q];
        const float xv[4] = {x4.x, x4.y, x4.z, x4.w};
#pragma unroll
        for (int mm = 0; mm < 4; ++mm)
#pragma unroll
          for (int i = 0; i < 10; ++i)
            acc[i] = fmaf(xv[mm], wv[i - mm + 4], acc[i]);   // static idx in [1,13]
        wb -= 4; int wc = (wb < 0) ? 0 : wb;        // slide (clamped; pads are zeros)
#pragma unroll
        for (int k = 15; k >= 4; --k) wv[k] = wv[k - 4];
        float2 wA = *(const float2*)&wr[wc];
        float2 wB = *(const float2*)&wr[wc + 2];
        wv[0] = wA.x; wv[1] = wA.y; wv[2] = wB.x; wv[3] = wB.y;
      }
    }

    // exactly-once writeout: u0 = 80*col + 10*pb (even -> float2 stores)
    float* Ob = Og_ + (size_t)b * 320000 + 2560 * bx + 80 * col + 10 * pb;
#pragma unroll
    for (int s = 0; s < 5; ++s) {
      float2 v; v.x = acc[2 * s]; v.y = acc[2 * s + 1];
      *(float2*)&Ob[2 * s] = v;
    }
  }
}

extern "C" void kernel_launch(void* const* d_in, const int* in_sizes, int n_in,
                              void* d_out, int out_size, void* d_ws, size_t ws_size,
                              hipStream_t stream) {
  const float* H     = (const float*)d_in[0];   // [32,4000,65] fp32
  const float* noise = (const float*)d_in[1];   // [32,4000,80] fp32
  float* out = (float*)d_out;                   // [32,320000] fp32
  _Float16* M = (_Float16*)d_ws;                // 27,648 B of scratch
  (void)in_sizes; (void)n_in; (void)ws_size; (void)out_size;

  minit_kernel<<<54, 256, 0, stream>>>(M);      // rebuilt every call (ws re-poisoned)
  dim3 grid(125, 32, 1);
  fng_kernel<<<grid, NT, 0, stream>>>(H, noise, out, M);
}